// Round 16
// baseline (172.056 us; speedup 1.0000x reference)
//
#include <hip/hip_runtime.h>
#include <math.h>

#define B_    16
#define D_    512
#define T_    4096
#define CBN_  1024
#define CD_   8
#define NTOK_ (B_ * T_)   // 65536

typedef float f4_native __attribute__((ext_vector_type(4)));

// ws float offsets
#define WS_WIN_T  0         // [512][8]  w_in transposed [i][o]
#define WS_NCB    4096      // [1024][8] NEGATED normalized codebook
#define WS_QT     12288     // [1024][4] {||q||, ||q||^2, cc/2, 0}
#define WS_PCB    16384     // [1024][512] w_out @ cb^T + b_out
#define WS_BPART  540672    // [2048] per-block loss partials
#define WS_CTR    542720    // int counter for last-block finalize

#define OUT_OFF_LOSS 33554432               // commitment[16], then codebook[16]
#define OUT_OFF_IDX  33554464               // indices as float [65536]

// ---------------- k0: all precompute (w_in_t, neg-codebook, qtab, pcb) -------
__global__ __launch_bounds__(256) void k0_prep(const float* __restrict__ v_in,
                                               const float* __restrict__ g_in,
                                               const float* __restrict__ v_out,
                                               const float* __restrict__ g_out,
                                               const float* __restrict__ b_out,
                                               const float* __restrict__ codebook,
                                               float* __restrict__ ws) {
    int bid = blockIdx.x, tid = threadIdx.x;
    if (bid == 0) {
        if (tid == 0) ((int*)ws)[WS_CTR] = 0;   // reset finalize counter
        // w_in_t[i][o] = g_in[o] * v_in[o][i] / ||v_in[o,:]||
        __shared__ float part[8][33];
        __shared__ float rn[8];
        int o = tid >> 5;       // 0..7
        int g = tid & 31;       // 0..31
        float s = 0.f;
        for (int i = g * 16; i < g * 16 + 16; ++i) { float x = v_in[o * 512 + i]; s += x * x; }
        part[o][g] = s;
        __syncthreads();
        if (tid < 8) {
            float t2 = 0.f;
            for (int gg = 0; gg < 32; ++gg) t2 += part[tid][gg];
            rn[tid] = g_in[tid] / sqrtf(t2);
        }
        __syncthreads();
        for (int ii = 0; ii < 2; ++ii) {
            int i = tid * 2 + ii;
#pragma unroll
            for (int oo = 0; oo < 8; ++oo)
                ws[WS_WIN_T + i * 8 + oo] = v_in[oo * 512 + i] * rn[oo];
        }
    } else if (bid <= 4) {
        // negated normalized codebook + {qn, sw, cc/2}
        int e = (bid - 1) * 256 + tid;
        const float* c = codebook + (size_t)e * 8;
        float v[8]; float s = 0.f;
#pragma unroll
        for (int j = 0; j < 8; ++j) { v[j] = c[j]; s += v[j] * v[j]; }
        float qn = sqrtf(s);
        float rn = 1.0f / fmaxf(qn, 1e-12f);
        float cs = 0.f;
        float* o = ws + WS_NCB + (size_t)e * 8;
#pragma unroll
        for (int j = 0; j < 8; ++j) { float cn = v[j] * rn; o[j] = -cn; cs += cn * cn; }
        float* q = ws + WS_QT + (size_t)e * 4;
        q[0] = qn; q[1] = s; q[2] = cs * 0.5f; q[3] = 0.f;
    } else {
        // pcb[e][o] = b_out[o] + sum_j w_out[o][j]*cb[e][j]
        int e = bid - 5;
        const float4* cq = (const float4*)(codebook + (size_t)e * 8);
        float4 q0 = cq[0], q1 = cq[1];
        float2 res; float* rp = &res.x;
#pragma unroll
        for (int ii = 0; ii < 2; ++ii) {
            int o = tid * 2 + ii;
            const float4* vr = (const float4*)(v_out + (size_t)o * 8);
            float4 va = vr[0], vb = vr[1];
            float s = va.x * va.x + va.y * va.y + va.z * va.z + va.w * va.w
                    + vb.x * vb.x + vb.y * vb.y + vb.z * vb.z + vb.w * vb.w;
            float rn = g_out[o] / sqrtf(s);
            float x = b_out[o];
            x = fmaf(va.x * rn, q0.x, x); x = fmaf(va.y * rn, q0.y, x);
            x = fmaf(va.z * rn, q0.z, x); x = fmaf(va.w * rn, q0.w, x);
            x = fmaf(vb.x * rn, q1.x, x); x = fmaf(vb.y * rn, q1.y, x);
            x = fmaf(vb.z * rn, q1.z, x); x = fmaf(vb.w * rn, q1.w, x);
            rp[ii] = x;
        }
        ((float2*)(ws + WS_PCB + (size_t)e * 512))[tid] = res;
    }
}

// ============ main fused kernel (R14 + float4 stores + fused finalize) =======
// grid 2048 x 128 threads (2 waves). Block = 32 tokens: b = blk>>7,
// tb = (blk&127)*32. ph1: 8-way row split; thread (p = tid>>4 in 0..7,
// tq = tid&15) covers rows [p*64,+64) x 2 tokens via float2 z loads (64 loads).
// ph2: lanes 0-31 finalize z_e (bias + 8 partials ascending). ph3: wave wv
// scans entries [wv*512,+512) as 8/lane, butterfly per token. ph4: lanes 0-31
// merge + loss. ph5: pcb-gather rows [32p5,+32) x 4 tokens, float4 NT stores.
// Tail: last block (atomic counter) writes the 32 loss floats.
__global__ __launch_bounds__(128, 4) void vq_main(const float* __restrict__ z,
                                                  const float* __restrict__ b_in,
                                                  const float* __restrict__ ws,
                                                  float* __restrict__ d_out,
                                                  float* __restrict__ wsm) {
    __shared__ float part[8 * 32 * 9];   // 9.2 KB, stride 9
    __shared__ float enorm[32 * 12];     // 1.5 KB: e[8], a, nrm2, zen, pad
    __shared__ float cand_d[64];
    __shared__ int   cand_i[64];
    __shared__ int   idxl[32];
    __shared__ int   isLast;

    int tid = threadIdx.x;
    int wv = tid >> 6;
    int l  = tid & 63;
    int p  = tid >> 4;        // 0..7 row octant
    int tq = tid & 15;        // token pair index
    int blk = blockIdx.x;
    int b = blk >> 7;
    int tb = (blk & 127) << 5;

    // ---- ph1: in_proj partials; rows [p*64,+64) x tokens {2tq, 2tq+1} ----
    {
        float a0[8], a1[8];
#pragma unroll
        for (int j = 0; j < 8; ++j) { a0[j] = 0.f; a1[j] = 0.f; }
        const float* zp = z + (size_t)b * D_ * T_ + (size_t)(p * 64) * T_ + tb + tq * 2;
        const float4* wp = ((const float4*)(ws + WS_WIN_T)) + p * 128;
#pragma unroll 16
        for (int i = 0; i < 64; ++i) {
            float2 v = *(const float2*)(zp + (size_t)i * T_);
            float4 wa = wp[i * 2];
            float4 wb = wp[i * 2 + 1];
            a0[0] = fmaf(wa.x, v.x, a0[0]); a1[0] = fmaf(wa.x, v.y, a1[0]);
            a0[1] = fmaf(wa.y, v.x, a0[1]); a1[1] = fmaf(wa.y, v.y, a1[1]);
            a0[2] = fmaf(wa.z, v.x, a0[2]); a1[2] = fmaf(wa.z, v.y, a1[2]);
            a0[3] = fmaf(wa.w, v.x, a0[3]); a1[3] = fmaf(wa.w, v.y, a1[3]);
            a0[4] = fmaf(wb.x, v.x, a0[4]); a1[4] = fmaf(wb.x, v.y, a1[4]);
            a0[5] = fmaf(wb.y, v.x, a0[5]); a1[5] = fmaf(wb.y, v.y, a1[5]);
            a0[6] = fmaf(wb.z, v.x, a0[6]); a1[6] = fmaf(wb.z, v.y, a1[6]);
            a0[7] = fmaf(wb.w, v.x, a0[7]); a1[7] = fmaf(wb.w, v.y, a1[7]);
        }
        float* pp0 = &part[(p * 32 + tq * 2) * 9];
        float* pp1 = &part[(p * 32 + tq * 2 + 1) * 9];
#pragma unroll
        for (int j = 0; j < 8; ++j) { pp0[j] = a0[j]; pp1[j] = a1[j]; }
    }
    __syncthreads();

    // ---- ph2: lanes 0-31 finalize z_e (bias + 8 partials ascending) ----
    if (tid < 32) {
        float ze[8];
#pragma unroll
        for (int j = 0; j < 8; ++j) ze[j] = b_in[j];
#pragma unroll
        for (int pp = 0; pp < 8; ++pp)
#pragma unroll
            for (int j = 0; j < 8; ++j) ze[j] += part[(pp * 32 + tid) * 9 + j];
        float nrm2 = ze[0] * ze[0] + ze[1] * ze[1] + ze[2] * ze[2] + ze[3] * ze[3]
                   + ze[4] * ze[4] + ze[5] * ze[5] + ze[6] * ze[6] + ze[7] * ze[7];
        float zen = fmaxf(sqrtf(nrm2), 1e-12f);
        float r = 1.0f / zen;
        float e0 = ze[0] * r, e1 = ze[1] * r, e2 = ze[2] * r, e3 = ze[3] * r;
        float e4 = ze[4] * r, e5 = ze[5] * r, e6 = ze[6] * r, e7 = ze[7] * r;
        float a = e0 * e0 + e1 * e1 + e2 * e2 + e3 * e3
                + e4 * e4 + e5 * e5 + e6 * e6 + e7 * e7;
        float* ep = &enorm[tid * 12];
        ep[0] = e0; ep[1] = e1; ep[2] = e2; ep[3] = e3;
        ep[4] = e4; ep[5] = e5; ep[6] = e6; ep[7] = e7;
        ep[8] = a; ep[9] = nrm2; ep[10] = zen; ep[11] = 0.f;
    }

    // ---- load 8 neg-codebook entries/lane: e = wv*512 + k*64 + l ----
    float nc[8][8]; float c2[8];
    int ebase = wv * 512;
#pragma unroll
    for (int k = 0; k < 8; ++k) {
        int e = ebase + k * 64 + l;
        const float4* cp = (const float4*)(ws + WS_NCB + (size_t)e * 8);
        float4 p0 = cp[0], p1 = cp[1];
        nc[k][0] = p0.x; nc[k][1] = p0.y; nc[k][2] = p0.z; nc[k][3] = p0.w;
        nc[k][4] = p1.x; nc[k][5] = p1.y; nc[k][6] = p1.z; nc[k][7] = p1.w;
        c2[k] = ws[WS_QT + (size_t)e * 4 + 2];
    }
    __syncthreads();

    // ---- ph3: score = cc/2 - dot (argmin-equivalent); butterfly lex-min ----
    for (int s = 0; s < 32; ++s) {
        float4 E0 = ((float4*)enorm)[s * 3 + 0];
        float4 E1 = ((float4*)enorm)[s * 3 + 1];
        float sb = 3.4e38f; int bi = 0x7fffffff;
#pragma unroll
        for (int k = 0; k < 8; ++k) {
            float sc = fmaf(nc[k][0], E0.x, c2[k]);
            sc = fmaf(nc[k][1], E0.y, sc);
            sc = fmaf(nc[k][2], E0.z, sc);
            sc = fmaf(nc[k][3], E0.w, sc);
            sc = fmaf(nc[k][4], E1.x, sc);
            sc = fmaf(nc[k][5], E1.y, sc);
            sc = fmaf(nc[k][6], E1.z, sc);
            sc = fmaf(nc[k][7], E1.w, sc);
            int e = ebase + k * 64 + l;
            if (sc < sb) { sb = sc; bi = e; }   // strict < -> first-min
        }
#pragma unroll
        for (int off = 1; off < 64; off <<= 1) {
            float ov = __shfl_xor(sb, off, 64);
            int   oi = __shfl_xor(bi, off, 64);
            if (ov < sb || (ov == sb && oi < bi)) { sb = ov; bi = oi; }
        }
        if (l == 0) { cand_d[wv * 32 + s] = sb; cand_i[wv * 32 + s] = bi; }
    }
    __syncthreads();

    // ---- ph4: lanes 0-31 merge the two waves + loss, one parallel pass ----
    if (tid < 32) {
        float d0 = cand_d[tid];       int i0 = cand_i[tid];
        float d1 = cand_d[32 + tid];  int i1 = cand_i[32 + tid];
        if (d1 < d0) { d0 = d1; i0 = i1; }   // ranges disjoint; wave0 wins ties
        idxl[tid] = i0;
        int tok = blk * 32 + tid;
        d_out[OUT_OFF_IDX + tok] = (float)i0;
        float nrm2 = enorm[tid * 12 + 9], zen = enorm[tid * 12 + 10];
        float4 qt = ((const float4*)(ws + WS_QT))[i0];   // {qn, sw, cc2, 0}
        float dot = qt.z - d0;
        float lv = nrm2 - 2.0f * dot * zen * qt.x + qt.y;
#pragma unroll
        for (int off = 1; off < 32; off <<= 1) lv += __shfl_xor(lv, off, 64);
        if (tid == 0) wsm[WS_BPART + blk] = lv;
    }
    __syncthreads();

    // ---- ph5: pcb-gather; rows [32p5,+32) x 4 tokens, float4 NT stores ----
    {
        int p5 = tid >> 3;        // 0..15 row group
        int q5 = tid & 7;         // token quad
        int i0 = idxl[q5 * 4 + 0], i1 = idxl[q5 * 4 + 1];
        int i2 = idxl[q5 * 4 + 2], i3 = idxl[q5 * 4 + 3];
        const float4* pr0 = (const float4*)(ws + WS_PCB + (size_t)i0 * 512 + p5 * 32);
        const float4* pr1 = (const float4*)(ws + WS_PCB + (size_t)i1 * 512 + p5 * 32);
        const float4* pr2 = (const float4*)(ws + WS_PCB + (size_t)i2 * 512 + p5 * 32);
        const float4* pr3 = (const float4*)(ws + WS_PCB + (size_t)i3 * 512 + p5 * 32);
        float* op = d_out + (size_t)b * D_ * T_ + (size_t)(p5 * 32) * T_ + tb + q5 * 4;
#pragma unroll 4
        for (int k = 0; k < 8; ++k) {
            float4 A = pr0[k], Bv = pr1[k], C = pr2[k], Dv = pr3[k];
            f4_native r0 = {A.x, Bv.x, C.x, Dv.x};
            f4_native r1 = {A.y, Bv.y, C.y, Dv.y};
            f4_native r2 = {A.z, Bv.z, C.z, Dv.z};
            f4_native r3 = {A.w, Bv.w, C.w, Dv.w};
            __builtin_nontemporal_store(r0, (f4_native*)(op + (size_t)(k * 4 + 0) * T_));
            __builtin_nontemporal_store(r1, (f4_native*)(op + (size_t)(k * 4 + 1) * T_));
            __builtin_nontemporal_store(r2, (f4_native*)(op + (size_t)(k * 4 + 2) * T_));
            __builtin_nontemporal_store(r3, (f4_native*)(op + (size_t)(k * 4 + 3) * T_));
        }
    }

    // ---- tail: last block finalizes losses ----
    if (tid == 0) {
        __threadfence();
        int old = atomicAdd((int*)wsm + WS_CTR, 1);
        isLast = (old == 2047);
    }
    __syncthreads();
    if (isLast) {
        __threadfence();
        if (tid < B_) {
            volatile const float* bp = wsm + WS_BPART;
            float s = 0.f;
            for (int k = 0; k < 128; ++k) s += bp[tid * 128 + k];
            float m = s * (1.0f / (CD_ * T_));
            d_out[OUT_OFF_LOSS + tid] = m;
            d_out[OUT_OFF_LOSS + 16 + tid] = m;
        }
    }
}

// ---------------- launch -----------------------------------------------------
extern "C" void kernel_launch(void* const* d_in, const int* in_sizes, int n_in,
                              void* d_out, int out_size, void* d_ws, size_t ws_size,
                              hipStream_t stream) {
    (void)in_sizes; (void)n_in; (void)out_size; (void)ws_size;
    const float* z        = (const float*)d_in[0];
    const float* v_in     = (const float*)d_in[1];
    const float* g_in     = (const float*)d_in[2];
    const float* b_in     = (const float*)d_in[3];
    const float* v_out    = (const float*)d_in[4];
    const float* g_out    = (const float*)d_in[5];
    const float* b_out    = (const float*)d_in[6];
    const float* codebook = (const float*)d_in[7];
    float* ws  = (float*)d_ws;
    float* out = (float*)d_out;

    hipLaunchKernelGGL(k0_prep, dim3(5 + CBN_), dim3(256), 0, stream,
                       v_in, g_in, v_out, g_out, b_out, codebook, ws);
    hipLaunchKernelGGL(vq_main, dim3(NTOK_ / 32), dim3(128), 0, stream,
                       z, b_in, ws, out, ws);
}

// Round 17
// 86.265 us; speedup vs baseline: 1.9945x; 1.9945x over previous
//
#include <hip/hip_runtime.h>
#include <math.h>

#define B_    16
#define D_    512
#define T_    4096
#define CBN_  1024
#define CD_   8
#define NTOK_ (B_ * T_)   // 65536

typedef float f4_native __attribute__((ext_vector_type(4)));

// ws float offsets
#define WS_WIN_T  0         // [512][8]  w_in transposed [i][o]
#define WS_NCB    4096      // [1024][8] NEGATED normalized codebook
#define WS_QT     12288     // [1024][4] {||q||, ||q||^2, cc/2, 0}
#define WS_PCB    16384     // [1024][512] w_out @ cb^T + b_out
#define WS_BPART  540672    // [2048] per-block loss partials

#define OUT_OFF_LOSS 33554432               // commitment[16], then codebook[16]
#define OUT_OFF_IDX  33554464               // indices as float [65536]

// ---------------- k0: all precompute (w_in_t, neg-codebook, qtab, pcb) -------
__global__ __launch_bounds__(256) void k0_prep(const float* __restrict__ v_in,
                                               const float* __restrict__ g_in,
                                               const float* __restrict__ v_out,
                                               const float* __restrict__ g_out,
                                               const float* __restrict__ b_out,
                                               const float* __restrict__ codebook,
                                               float* __restrict__ ws) {
    int bid = blockIdx.x, tid = threadIdx.x;
    if (bid == 0) {
        // w_in_t[i][o] = g_in[o] * v_in[o][i] / ||v_in[o,:]||
        __shared__ float part[8][33];
        __shared__ float rn[8];
        int o = tid >> 5;       // 0..7
        int g = tid & 31;       // 0..31
        float s = 0.f;
        for (int i = g * 16; i < g * 16 + 16; ++i) { float x = v_in[o * 512 + i]; s += x * x; }
        part[o][g] = s;
        __syncthreads();
        if (tid < 8) {
            float t2 = 0.f;
            for (int gg = 0; gg < 32; ++gg) t2 += part[tid][gg];
            rn[tid] = g_in[tid] / sqrtf(t2);
        }
        __syncthreads();
        for (int ii = 0; ii < 2; ++ii) {
            int i = tid * 2 + ii;
#pragma unroll
            for (int oo = 0; oo < 8; ++oo)
                ws[WS_WIN_T + i * 8 + oo] = v_in[oo * 512 + i] * rn[oo];
        }
    } else if (bid <= 4) {
        // negated normalized codebook + {qn, sw, cc/2}
        int e = (bid - 1) * 256 + tid;
        const float* c = codebook + (size_t)e * 8;
        float v[8]; float s = 0.f;
#pragma unroll
        for (int j = 0; j < 8; ++j) { v[j] = c[j]; s += v[j] * v[j]; }
        float qn = sqrtf(s);
        float rn = 1.0f / fmaxf(qn, 1e-12f);
        float cs = 0.f;
        float* o = ws + WS_NCB + (size_t)e * 8;
#pragma unroll
        for (int j = 0; j < 8; ++j) { float cn = v[j] * rn; o[j] = -cn; cs += cn * cn; }
        float* q = ws + WS_QT + (size_t)e * 4;
        q[0] = qn; q[1] = s; q[2] = cs * 0.5f; q[3] = 0.f;
    } else {
        // pcb[e][o] = b_out[o] + sum_j w_out[o][j]*cb[e][j]
        int e = bid - 5;
        const float4* cq = (const float4*)(codebook + (size_t)e * 8);
        float4 q0 = cq[0], q1 = cq[1];
        float2 res; float* rp = &res.x;
#pragma unroll
        for (int ii = 0; ii < 2; ++ii) {
            int o = tid * 2 + ii;
            const float4* vr = (const float4*)(v_out + (size_t)o * 8);
            float4 va = vr[0], vb = vr[1];
            float s = va.x * va.x + va.y * va.y + va.z * va.z + va.w * va.w
                    + vb.x * vb.x + vb.y * vb.y + vb.z * vb.z + vb.w * vb.w;
            float rn = g_out[o] / sqrtf(s);
            float x = b_out[o];
            x = fmaf(va.x * rn, q0.x, x); x = fmaf(va.y * rn, q0.y, x);
            x = fmaf(va.z * rn, q0.z, x); x = fmaf(va.w * rn, q0.w, x);
            x = fmaf(vb.x * rn, q1.x, x); x = fmaf(vb.y * rn, q1.y, x);
            x = fmaf(vb.z * rn, q1.z, x); x = fmaf(vb.w * rn, q1.w, x);
            rp[ii] = x;
        }
        ((float2*)(ws + WS_PCB + (size_t)e * 512))[tid] = res;
    }
}

// ============ main fused kernel (R14 + float4 NT stores in ph5) ==============
// grid 2048 x 128 threads (2 waves). Block = 32 tokens: b = blk>>7,
// tb = (blk&127)*32. ph1: 8-way row split; thread (p = tid>>4 in 0..7,
// tq = tid&15) covers rows [p*64,+64) x 2 tokens via float2 z loads (64 loads).
// ph2: lanes 0-31 finalize z_e (bias + 8 partials ascending). ph3: wave wv
// scans entries [wv*512,+512) as 8/lane, butterfly per token. ph4: lanes 0-31
// merge waves + loss. ph5: pcb-gather rows [32p5,+32) x 4 tokens, float4 NT.
__global__ __launch_bounds__(128, 4) void vq_main(const float* __restrict__ z,
                                                  const float* __restrict__ b_in,
                                                  const float* __restrict__ ws,
                                                  float* __restrict__ d_out,
                                                  float* __restrict__ bpart) {
    __shared__ float part[8 * 32 * 9];   // 9.2 KB, stride 9
    __shared__ float enorm[32 * 12];     // 1.5 KB: e[8], a, nrm2, zen, pad
    __shared__ float cand_d[64];
    __shared__ int   cand_i[64];
    __shared__ int   idxl[32];

    int tid = threadIdx.x;
    int wv = tid >> 6;
    int l  = tid & 63;
    int p  = tid >> 4;        // 0..7 row octant
    int tq = tid & 15;        // token pair index
    int blk = blockIdx.x;
    int b = blk >> 7;
    int tb = (blk & 127) << 5;

    // ---- ph1: in_proj partials; rows [p*64,+64) x tokens {2tq, 2tq+1} ----
    {
        float a0[8], a1[8];
#pragma unroll
        for (int j = 0; j < 8; ++j) { a0[j] = 0.f; a1[j] = 0.f; }
        const float* zp = z + (size_t)b * D_ * T_ + (size_t)(p * 64) * T_ + tb + tq * 2;
        const float4* wp = ((const float4*)(ws + WS_WIN_T)) + p * 128;
#pragma unroll 16
        for (int i = 0; i < 64; ++i) {
            float2 v = *(const float2*)(zp + (size_t)i * T_);
            float4 wa = wp[i * 2];
            float4 wb = wp[i * 2 + 1];
            a0[0] = fmaf(wa.x, v.x, a0[0]); a1[0] = fmaf(wa.x, v.y, a1[0]);
            a0[1] = fmaf(wa.y, v.x, a0[1]); a1[1] = fmaf(wa.y, v.y, a1[1]);
            a0[2] = fmaf(wa.z, v.x, a0[2]); a1[2] = fmaf(wa.z, v.y, a1[2]);
            a0[3] = fmaf(wa.w, v.x, a0[3]); a1[3] = fmaf(wa.w, v.y, a1[3]);
            a0[4] = fmaf(wb.x, v.x, a0[4]); a1[4] = fmaf(wb.x, v.y, a1[4]);
            a0[5] = fmaf(wb.y, v.x, a0[5]); a1[5] = fmaf(wb.y, v.y, a1[5]);
            a0[6] = fmaf(wb.z, v.x, a0[6]); a1[6] = fmaf(wb.z, v.y, a1[6]);
            a0[7] = fmaf(wb.w, v.x, a0[7]); a1[7] = fmaf(wb.w, v.y, a1[7]);
        }
        float* pp0 = &part[(p * 32 + tq * 2) * 9];
        float* pp1 = &part[(p * 32 + tq * 2 + 1) * 9];
#pragma unroll
        for (int j = 0; j < 8; ++j) { pp0[j] = a0[j]; pp1[j] = a1[j]; }
    }
    __syncthreads();

    // ---- ph2: lanes 0-31 finalize z_e (bias + 8 partials ascending) ----
    if (tid < 32) {
        float ze[8];
#pragma unroll
        for (int j = 0; j < 8; ++j) ze[j] = b_in[j];
#pragma unroll
        for (int pp = 0; pp < 8; ++pp)
#pragma unroll
            for (int j = 0; j < 8; ++j) ze[j] += part[(pp * 32 + tid) * 9 + j];
        float nrm2 = ze[0] * ze[0] + ze[1] * ze[1] + ze[2] * ze[2] + ze[3] * ze[3]
                   + ze[4] * ze[4] + ze[5] * ze[5] + ze[6] * ze[6] + ze[7] * ze[7];
        float zen = fmaxf(sqrtf(nrm2), 1e-12f);
        float r = 1.0f / zen;
        float e0 = ze[0] * r, e1 = ze[1] * r, e2 = ze[2] * r, e3 = ze[3] * r;
        float e4 = ze[4] * r, e5 = ze[5] * r, e6 = ze[6] * r, e7 = ze[7] * r;
        float a = e0 * e0 + e1 * e1 + e2 * e2 + e3 * e3
                + e4 * e4 + e5 * e5 + e6 * e6 + e7 * e7;
        float* ep = &enorm[tid * 12];
        ep[0] = e0; ep[1] = e1; ep[2] = e2; ep[3] = e3;
        ep[4] = e4; ep[5] = e5; ep[6] = e6; ep[7] = e7;
        ep[8] = a; ep[9] = nrm2; ep[10] = zen; ep[11] = 0.f;
    }

    // ---- load 8 neg-codebook entries/lane: e = wv*512 + k*64 + l ----
    float nc[8][8]; float c2[8];
    int ebase = wv * 512;
#pragma unroll
    for (int k = 0; k < 8; ++k) {
        int e = ebase + k * 64 + l;
        const float4* cp = (const float4*)(ws + WS_NCB + (size_t)e * 8);
        float4 p0 = cp[0], p1 = cp[1];
        nc[k][0] = p0.x; nc[k][1] = p0.y; nc[k][2] = p0.z; nc[k][3] = p0.w;
        nc[k][4] = p1.x; nc[k][5] = p1.y; nc[k][6] = p1.z; nc[k][7] = p1.w;
        c2[k] = ws[WS_QT + (size_t)e * 4 + 2];
    }
    __syncthreads();

    // ---- ph3: score = cc/2 - dot (argmin-equivalent); butterfly lex-min ----
    for (int s = 0; s < 32; ++s) {
        float4 E0 = ((float4*)enorm)[s * 3 + 0];
        float4 E1 = ((float4*)enorm)[s * 3 + 1];
        float sb = 3.4e38f; int bi = 0x7fffffff;
#pragma unroll
        for (int k = 0; k < 8; ++k) {
            float sc = fmaf(nc[k][0], E0.x, c2[k]);
            sc = fmaf(nc[k][1], E0.y, sc);
            sc = fmaf(nc[k][2], E0.z, sc);
            sc = fmaf(nc[k][3], E0.w, sc);
            sc = fmaf(nc[k][4], E1.x, sc);
            sc = fmaf(nc[k][5], E1.y, sc);
            sc = fmaf(nc[k][6], E1.z, sc);
            sc = fmaf(nc[k][7], E1.w, sc);
            int e = ebase + k * 64 + l;
            if (sc < sb) { sb = sc; bi = e; }   // strict < -> first-min
        }
#pragma unroll
        for (int off = 1; off < 64; off <<= 1) {
            float ov = __shfl_xor(sb, off, 64);
            int   oi = __shfl_xor(bi, off, 64);
            if (ov < sb || (ov == sb && oi < bi)) { sb = ov; bi = oi; }
        }
        if (l == 0) { cand_d[wv * 32 + s] = sb; cand_i[wv * 32 + s] = bi; }
    }
    __syncthreads();

    // ---- ph4: lanes 0-31 merge the two waves + loss, one parallel pass ----
    if (tid < 32) {
        float d0 = cand_d[tid];       int i0 = cand_i[tid];
        float d1 = cand_d[32 + tid];  int i1 = cand_i[32 + tid];
        if (d1 < d0) { d0 = d1; i0 = i1; }   // ranges disjoint; wave0 wins ties
        idxl[tid] = i0;
        int tok = blk * 32 + tid;
        d_out[OUT_OFF_IDX + tok] = (float)i0;
        float nrm2 = enorm[tid * 12 + 9], zen = enorm[tid * 12 + 10];
        float4 qt = ((const float4*)(ws + WS_QT))[i0];   // {qn, sw, cc2, 0}
        float dot = qt.z - d0;
        float lv = nrm2 - 2.0f * dot * zen * qt.x + qt.y;
#pragma unroll
        for (int off = 1; off < 32; off <<= 1) lv += __shfl_xor(lv, off, 64);
        if (tid == 0) bpart[blk] = lv;
    }
    __syncthreads();

    // ---- ph5: pcb-gather; rows [32p5,+32) x 4 tokens, float4 NT stores ----
    {
        int p5 = tid >> 3;        // 0..15 row group
        int q5 = tid & 7;         // token quad
        int i0 = idxl[q5 * 4 + 0], i1 = idxl[q5 * 4 + 1];
        int i2 = idxl[q5 * 4 + 2], i3 = idxl[q5 * 4 + 3];
        const float4* pr0 = (const float4*)(ws + WS_PCB + (size_t)i0 * 512 + p5 * 32);
        const float4* pr1 = (const float4*)(ws + WS_PCB + (size_t)i1 * 512 + p5 * 32);
        const float4* pr2 = (const float4*)(ws + WS_PCB + (size_t)i2 * 512 + p5 * 32);
        const float4* pr3 = (const float4*)(ws + WS_PCB + (size_t)i3 * 512 + p5 * 32);
        float* op = d_out + (size_t)b * D_ * T_ + (size_t)(p5 * 32) * T_ + tb + q5 * 4;
#pragma unroll 4
        for (int k = 0; k < 8; ++k) {
            float4 A = pr0[k], Bv = pr1[k], C = pr2[k], Dv = pr3[k];
            f4_native r0 = {A.x, Bv.x, C.x, Dv.x};
            f4_native r1 = {A.y, Bv.y, C.y, Dv.y};
            f4_native r2 = {A.z, Bv.z, C.z, Dv.z};
            f4_native r3 = {A.w, Bv.w, C.w, Dv.w};
            __builtin_nontemporal_store(r0, (f4_native*)(op + (size_t)(k * 4 + 0) * T_));
            __builtin_nontemporal_store(r1, (f4_native*)(op + (size_t)(k * 4 + 1) * T_));
            __builtin_nontemporal_store(r2, (f4_native*)(op + (size_t)(k * 4 + 2) * T_));
            __builtin_nontemporal_store(r3, (f4_native*)(op + (size_t)(k * 4 + 3) * T_));
        }
    }
}

// ============ finalize: per-batch loss reduction =============================
__global__ __launch_bounds__(64) void vq_finalize(const float* __restrict__ bpart,
                                                  float* __restrict__ d_out) {
    int tid = threadIdx.x;
    if (tid < B_) {
        float s = 0.f;
        for (int k = 0; k < 128; ++k) s += bpart[tid * 128 + k];
        float m = s * (1.0f / (CD_ * T_));
        d_out[OUT_OFF_LOSS + tid] = m;
        d_out[OUT_OFF_LOSS + 16 + tid] = m;
    }
}

// ---------------- launch -----------------------------------------------------
extern "C" void kernel_launch(void* const* d_in, const int* in_sizes, int n_in,
                              void* d_out, int out_size, void* d_ws, size_t ws_size,
                              hipStream_t stream) {
    (void)in_sizes; (void)n_in; (void)out_size; (void)ws_size;
    const float* z        = (const float*)d_in[0];
    const float* v_in     = (const float*)d_in[1];
    const float* g_in     = (const float*)d_in[2];
    const float* b_in     = (const float*)d_in[3];
    const float* v_out    = (const float*)d_in[4];
    const float* g_out    = (const float*)d_in[5];
    const float* b_out    = (const float*)d_in[6];
    const float* codebook = (const float*)d_in[7];
    float* ws  = (float*)d_ws;
    float* out = (float*)d_out;

    hipLaunchKernelGGL(k0_prep, dim3(5 + CBN_), dim3(256), 0, stream,
                       v_in, g_in, v_out, g_out, b_out, codebook, ws);
    hipLaunchKernelGGL(vq_main, dim3(NTOK_ / 32), dim3(128), 0, stream,
                       z, b_in, ws, out, ws + WS_BPART);
    hipLaunchKernelGGL(vq_finalize, dim3(1), dim3(64), 0, stream,
                       ws + WS_BPART, out);
}

// Round 18
// 77.798 us; speedup vs baseline: 2.2116x; 1.1088x over previous
//
#include <hip/hip_runtime.h>
#include <math.h>

#define B_    16
#define D_    512
#define T_    4096
#define CBN_  1024
#define CD_   8
#define NTOK_ (B_ * T_)   // 65536

typedef float f2_native __attribute__((ext_vector_type(2)));

// ws float offsets
#define WS_WIN_T  0         // [512][8]  w_in transposed [i][o]
#define WS_NCB    4096      // [1024][8] NEGATED normalized codebook
#define WS_QT     12288     // [1024][4] {||q||, ||q||^2, cc/2, 0}
#define WS_PCB    16384     // [1024][512] w_out @ cb^T + b_out
#define WS_BPART  540672    // [2048] per-block loss partials

#define OUT_OFF_LOSS 33554432               // commitment[16], then codebook[16]
#define OUT_OFF_IDX  33554464               // indices as float [65536]

// ---------------- k0: all precompute (w_in_t, neg-codebook, qtab, pcb) -------
__global__ __launch_bounds__(256) void k0_prep(const float* __restrict__ v_in,
                                               const float* __restrict__ g_in,
                                               const float* __restrict__ v_out,
                                               const float* __restrict__ g_out,
                                               const float* __restrict__ b_out,
                                               const float* __restrict__ codebook,
                                               float* __restrict__ ws) {
    int bid = blockIdx.x, tid = threadIdx.x;
    if (bid == 0) {
        // w_in_t[i][o] = g_in[o] * v_in[o][i] / ||v_in[o,:]||
        __shared__ float part[8][33];
        __shared__ float rn[8];
        int o = tid >> 5;       // 0..7
        int g = tid & 31;       // 0..31
        float s = 0.f;
        for (int i = g * 16; i < g * 16 + 16; ++i) { float x = v_in[o * 512 + i]; s += x * x; }
        part[o][g] = s;
        __syncthreads();
        if (tid < 8) {
            float t2 = 0.f;
            for (int gg = 0; gg < 32; ++gg) t2 += part[tid][gg];
            rn[tid] = g_in[tid] / sqrtf(t2);
        }
        __syncthreads();
        for (int ii = 0; ii < 2; ++ii) {
            int i = tid * 2 + ii;
#pragma unroll
            for (int oo = 0; oo < 8; ++oo)
                ws[WS_WIN_T + i * 8 + oo] = v_in[oo * 512 + i] * rn[oo];
        }
    } else if (bid <= 4) {
        // negated normalized codebook + {qn, sw, cc/2}
        int e = (bid - 1) * 256 + tid;
        const float* c = codebook + (size_t)e * 8;
        float v[8]; float s = 0.f;
#pragma unroll
        for (int j = 0; j < 8; ++j) { v[j] = c[j]; s += v[j] * v[j]; }
        float qn = sqrtf(s);
        float rn = 1.0f / fmaxf(qn, 1e-12f);
        float cs = 0.f;
        float* o = ws + WS_NCB + (size_t)e * 8;
#pragma unroll
        for (int j = 0; j < 8; ++j) { float cn = v[j] * rn; o[j] = -cn; cs += cn * cn; }
        float* q = ws + WS_QT + (size_t)e * 4;
        q[0] = qn; q[1] = s; q[2] = cs * 0.5f; q[3] = 0.f;
    } else {
        // pcb[e][o] = b_out[o] + sum_j w_out[o][j]*cb[e][j]
        int e = bid - 5;
        const float4* cq = (const float4*)(codebook + (size_t)e * 8);
        float4 q0 = cq[0], q1 = cq[1];
        float2 res; float* rp = &res.x;
#pragma unroll
        for (int ii = 0; ii < 2; ++ii) {
            int o = tid * 2 + ii;
            const float4* vr = (const float4*)(v_out + (size_t)o * 8);
            float4 va = vr[0], vb = vr[1];
            float s = va.x * va.x + va.y * va.y + va.z * va.z + va.w * va.w
                    + vb.x * vb.x + vb.y * vb.y + vb.z * vb.z + vb.w * vb.w;
            float rn = g_out[o] / sqrtf(s);
            float x = b_out[o];
            x = fmaf(va.x * rn, q0.x, x); x = fmaf(va.y * rn, q0.y, x);
            x = fmaf(va.z * rn, q0.z, x); x = fmaf(va.w * rn, q0.w, x);
            x = fmaf(vb.x * rn, q1.x, x); x = fmaf(vb.y * rn, q1.y, x);
            x = fmaf(vb.z * rn, q1.z, x); x = fmaf(vb.w * rn, q1.w, x);
            rp[ii] = x;
        }
        ((float2*)(ws + WS_PCB + (size_t)e * 512))[tid] = res;
    }
}

// ============ main fused kernel (R14 + 32-deep ph1 load batching) ============
// grid 2048 x 128 threads (2 waves). Block = 32 tokens: b = blk>>7,
// tb = (blk&127)*32. ph1: 8-way row split; thread (p = tid>>4 in 0..7,
// tq = tid&15) covers rows [p*64,+64) x 2 tokens; 2 half-passes of {32 float2
// z loads into regs, then 32x16 FMA} -> 2 latency exposures instead of 4.
// ph2: lanes 0-31 finalize z_e (bias + 8 partials ascending). ph3: wave wv
// scans entries [wv*512,+512) as 8/lane, butterfly per token. ph4: lanes 0-31
// merge waves + loss. ph5: pcb-gather, float2 NT stores (R14-identical).
__global__ __launch_bounds__(128, 4) void vq_main(const float* __restrict__ z,
                                                  const float* __restrict__ b_in,
                                                  const float* __restrict__ ws,
                                                  float* __restrict__ d_out,
                                                  float* __restrict__ bpart) {
    __shared__ float part[8 * 32 * 9];   // 9.2 KB, stride 9
    __shared__ float enorm[32 * 12];     // 1.5 KB: e[8], a, nrm2, zen, pad
    __shared__ float cand_d[64];
    __shared__ int   cand_i[64];
    __shared__ int   idxl[32];

    int tid = threadIdx.x;
    int wv = tid >> 6;
    int l  = tid & 63;
    int p  = tid >> 4;        // 0..7 row octant
    int tq = tid & 15;        // token pair index
    int blk = blockIdx.x;
    int b = blk >> 7;
    int tb = (blk & 127) << 5;

    // ---- ph1: in_proj partials; rows [p*64,+64) x tokens {2tq, 2tq+1} ----
    {
        float a0[8], a1[8];
#pragma unroll
        for (int j = 0; j < 8; ++j) { a0[j] = 0.f; a1[j] = 0.f; }
        const float* zp = z + (size_t)b * D_ * T_ + (size_t)(p * 64) * T_ + tb + tq * 2;
        const float4* wp = ((const float4*)(ws + WS_WIN_T)) + p * 128;
        for (int h = 0; h < 2; ++h) {
            float2 vz[32];
#pragma unroll
            for (int i = 0; i < 32; ++i)
                vz[i] = *(const float2*)(zp + (size_t)(h * 32 + i) * T_);
#pragma unroll
            for (int i = 0; i < 32; ++i) {
                int ii = h * 32 + i;
                float4 wa = wp[ii * 2];
                float4 wb = wp[ii * 2 + 1];
                float2 v = vz[i];
                a0[0] = fmaf(wa.x, v.x, a0[0]); a1[0] = fmaf(wa.x, v.y, a1[0]);
                a0[1] = fmaf(wa.y, v.x, a0[1]); a1[1] = fmaf(wa.y, v.y, a1[1]);
                a0[2] = fmaf(wa.z, v.x, a0[2]); a1[2] = fmaf(wa.z, v.y, a1[2]);
                a0[3] = fmaf(wa.w, v.x, a0[3]); a1[3] = fmaf(wa.w, v.y, a1[3]);
                a0[4] = fmaf(wb.x, v.x, a0[4]); a1[4] = fmaf(wb.x, v.y, a1[4]);
                a0[5] = fmaf(wb.y, v.x, a0[5]); a1[5] = fmaf(wb.y, v.y, a1[5]);
                a0[6] = fmaf(wb.z, v.x, a0[6]); a1[6] = fmaf(wb.z, v.y, a1[6]);
                a0[7] = fmaf(wb.w, v.x, a0[7]); a1[7] = fmaf(wb.w, v.y, a1[7]);
            }
        }
        float* pp0 = &part[(p * 32 + tq * 2) * 9];
        float* pp1 = &part[(p * 32 + tq * 2 + 1) * 9];
#pragma unroll
        for (int j = 0; j < 8; ++j) { pp0[j] = a0[j]; pp1[j] = a1[j]; }
    }
    __syncthreads();

    // ---- ph2: lanes 0-31 finalize z_e (bias + 8 partials ascending) ----
    if (tid < 32) {
        float ze[8];
#pragma unroll
        for (int j = 0; j < 8; ++j) ze[j] = b_in[j];
#pragma unroll
        for (int pp = 0; pp < 8; ++pp)
#pragma unroll
            for (int j = 0; j < 8; ++j) ze[j] += part[(pp * 32 + tid) * 9 + j];
        float nrm2 = ze[0] * ze[0] + ze[1] * ze[1] + ze[2] * ze[2] + ze[3] * ze[3]
                   + ze[4] * ze[4] + ze[5] * ze[5] + ze[6] * ze[6] + ze[7] * ze[7];
        float zen = fmaxf(sqrtf(nrm2), 1e-12f);
        float r = 1.0f / zen;
        float e0 = ze[0] * r, e1 = ze[1] * r, e2 = ze[2] * r, e3 = ze[3] * r;
        float e4 = ze[4] * r, e5 = ze[5] * r, e6 = ze[6] * r, e7 = ze[7] * r;
        float a = e0 * e0 + e1 * e1 + e2 * e2 + e3 * e3
                + e4 * e4 + e5 * e5 + e6 * e6 + e7 * e7;
        float* ep = &enorm[tid * 12];
        ep[0] = e0; ep[1] = e1; ep[2] = e2; ep[3] = e3;
        ep[4] = e4; ep[5] = e5; ep[6] = e6; ep[7] = e7;
        ep[8] = a; ep[9] = nrm2; ep[10] = zen; ep[11] = 0.f;
    }

    // ---- load 8 neg-codebook entries/lane: e = wv*512 + k*64 + l ----
    float nc[8][8]; float c2[8];
    int ebase = wv * 512;
#pragma unroll
    for (int k = 0; k < 8; ++k) {
        int e = ebase + k * 64 + l;
        const float4* cp = (const float4*)(ws + WS_NCB + (size_t)e * 8);
        float4 p0 = cp[0], p1 = cp[1];
        nc[k][0] = p0.x; nc[k][1] = p0.y; nc[k][2] = p0.z; nc[k][3] = p0.w;
        nc[k][4] = p1.x; nc[k][5] = p1.y; nc[k][6] = p1.z; nc[k][7] = p1.w;
        c2[k] = ws[WS_QT + (size_t)e * 4 + 2];
    }
    __syncthreads();

    // ---- ph3: score = cc/2 - dot (argmin-equivalent); butterfly lex-min ----
    for (int s = 0; s < 32; ++s) {
        float4 E0 = ((float4*)enorm)[s * 3 + 0];
        float4 E1 = ((float4*)enorm)[s * 3 + 1];
        float sb = 3.4e38f; int bi = 0x7fffffff;
#pragma unroll
        for (int k = 0; k < 8; ++k) {
            float sc = fmaf(nc[k][0], E0.x, c2[k]);
            sc = fmaf(nc[k][1], E0.y, sc);
            sc = fmaf(nc[k][2], E0.z, sc);
            sc = fmaf(nc[k][3], E0.w, sc);
            sc = fmaf(nc[k][4], E1.x, sc);
            sc = fmaf(nc[k][5], E1.y, sc);
            sc = fmaf(nc[k][6], E1.z, sc);
            sc = fmaf(nc[k][7], E1.w, sc);
            int e = ebase + k * 64 + l;
            if (sc < sb) { sb = sc; bi = e; }   // strict < -> first-min
        }
#pragma unroll
        for (int off = 1; off < 64; off <<= 1) {
            float ov = __shfl_xor(sb, off, 64);
            int   oi = __shfl_xor(bi, off, 64);
            if (ov < sb || (ov == sb && oi < bi)) { sb = ov; bi = oi; }
        }
        if (l == 0) { cand_d[wv * 32 + s] = sb; cand_i[wv * 32 + s] = bi; }
    }
    __syncthreads();

    // ---- ph4: lanes 0-31 merge the two waves + loss, one parallel pass ----
    if (tid < 32) {
        float d0 = cand_d[tid];       int i0 = cand_i[tid];
        float d1 = cand_d[32 + tid];  int i1 = cand_i[32 + tid];
        if (d1 < d0) { d0 = d1; i0 = i1; }   // ranges disjoint; wave0 wins ties
        idxl[tid] = i0;
        int tok = blk * 32 + tid;
        d_out[OUT_OFF_IDX + tok] = (float)i0;
        float nrm2 = enorm[tid * 12 + 9], zen = enorm[tid * 12 + 10];
        float4 qt = ((const float4*)(ws + WS_QT))[i0];   // {qn, sw, cc2, 0}
        float dot = qt.z - d0;
        float lv = nrm2 - 2.0f * dot * zen * qt.x + qt.y;
#pragma unroll
        for (int off = 1; off < 32; off <<= 1) lv += __shfl_xor(lv, off, 64);
        if (tid == 0) bpart[blk] = lv;
    }
    __syncthreads();

    // ---- ph5: pcb-gather; rows [p*64,+64) x 2 tokens, f2 NT stores ----
    {
        int i0 = idxl[tq * 2], i1 = idxl[tq * 2 + 1];
        const float4* pr0 = (const float4*)(ws + WS_PCB + (size_t)i0 * 512 + p * 64);
        const float4* pr1 = (const float4*)(ws + WS_PCB + (size_t)i1 * 512 + p * 64);
        float* op = d_out + (size_t)b * D_ * T_ + (size_t)(p * 64) * T_ + tb + tq * 2;
#pragma unroll 8
        for (int k = 0; k < 16; ++k) {
            float4 A = pr0[k];
            float4 Bv = pr1[k];
            f2_native r0 = {A.x, Bv.x};
            f2_native r1 = {A.y, Bv.y};
            f2_native r2 = {A.z, Bv.z};
            f2_native r3 = {A.w, Bv.w};
            __builtin_nontemporal_store(r0, (f2_native*)(op + (size_t)(k * 4 + 0) * T_));
            __builtin_nontemporal_store(r1, (f2_native*)(op + (size_t)(k * 4 + 1) * T_));
            __builtin_nontemporal_store(r2, (f2_native*)(op + (size_t)(k * 4 + 2) * T_));
            __builtin_nontemporal_store(r3, (f2_native*)(op + (size_t)(k * 4 + 3) * T_));
        }
    }
}

// ============ finalize: per-batch loss reduction =============================
__global__ __launch_bounds__(64) void vq_finalize(const float* __restrict__ bpart,
                                                  float* __restrict__ d_out) {
    int tid = threadIdx.x;
    if (tid < B_) {
        float s = 0.f;
        for (int k = 0; k < 128; ++k) s += bpart[tid * 128 + k];
        float m = s * (1.0f / (CD_ * T_));
        d_out[OUT_OFF_LOSS + tid] = m;
        d_out[OUT_OFF_LOSS + 16 + tid] = m;
    }
}

// ---------------- launch -----------------------------------------------------
extern "C" void kernel_launch(void* const* d_in, const int* in_sizes, int n_in,
                              void* d_out, int out_size, void* d_ws, size_t ws_size,
                              hipStream_t stream) {
    (void)in_sizes; (void)n_in; (void)out_size; (void)ws_size;
    const float* z        = (const float*)d_in[0];
    const float* v_in     = (const float*)d_in[1];
    const float* g_in     = (const float*)d_in[2];
    const float* b_in     = (const float*)d_in[3];
    const float* v_out    = (const float*)d_in[4];
    const float* g_out    = (const float*)d_in[5];
    const float* b_out    = (const float*)d_in[6];
    const float* codebook = (const float*)d_in[7];
    float* ws  = (float*)d_ws;
    float* out = (float*)d_out;

    hipLaunchKernelGGL(k0_prep, dim3(5 + CBN_), dim3(256), 0, stream,
                       v_in, g_in, v_out, g_out, b_out, codebook, ws);
    hipLaunchKernelGGL(vq_main, dim3(NTOK_ / 32), dim3(128), 0, stream,
                       z, b_in, ws, out, ws + WS_BPART);
    hipLaunchKernelGGL(vq_finalize, dim3(1), dim3(64), 0, stream,
                       ws + WS_BPART, out);
}